// Round 8
// baseline (1242.175 us; speedup 1.0000x reference)
//
#include <hip/hip_runtime.h>
#include <hip/hip_bf16.h>

typedef __bf16 bf16;
typedef __attribute__((ext_vector_type(8))) __bf16 bf16x8;
typedef __attribute__((ext_vector_type(4))) __bf16 bf16x4;
typedef __attribute__((ext_vector_type(4))) float f32x4;

#define MFMA_16x16x32(a, b, c) __builtin_amdgcn_mfma_f32_16x16x32_bf16(a, b, c, 0, 0, 0)

// Problem dims (fixed by the reference)
#define BATCH 4
#define SEQ   4096
#define HID   256
#define FFD   1024
#define MTOT  (BATCH * SEQ)   // 16384

// ---------------- prep kernels ----------------
__global__ void cast_x_kernel(const float* __restrict__ src, bf16* __restrict__ dst, int n4) {
    int i = blockIdx.x * blockDim.x + threadIdx.x;
    if (i < n4) {
        float4 v = ((const float4*)src)[i];
        bf16x4 o;
        o[0] = (bf16)v.x; o[1] = (bf16)v.y; o[2] = (bf16)v.z; o[3] = (bf16)v.w;
        ((bf16x4*)dst)[i] = o;
    }
}

// src: fp32 [R][C]  ->  dst: bf16 [C][R]   (dst[c][r] = src[r][c])
__global__ void transpose_cast_kernel(const float* __restrict__ src, bf16* __restrict__ dst,
                                      int R, int C) {
    int idx = blockIdx.x * blockDim.x + threadIdx.x;
    if (idx < R * C) {
        int r = idx / C, c = idx % C;
        dst[c * R + r] = (bf16)src[idx];
    }
}

// ---------------- QKV projection ----------------
// grid (MTOT/64, 12); blockIdx.y: 0-3 -> q cols, 4-7 -> k cols, 8-11 -> v cols
__global__ __launch_bounds__(256) void qkv_kernel(
    const bf16* __restrict__ xb,                       // [MTOT][256]
    const bf16* __restrict__ wqT, const bf16* __restrict__ wkT, const bf16* __restrict__ wvT,
    const float* __restrict__ bq, const float* __restrict__ bk, const float* __restrict__ bv,
    bf16* __restrict__ q, bf16* __restrict__ k, bf16* __restrict__ vT) // q,k: [MTOT][256]; vT: [B][256][SEQ]
{
    __shared__ bf16 vt[64][72];
    const int lane = threadIdx.x & 63, wave = threadIdx.x >> 6;
    const int g = lane >> 4, c = lane & 15;
    const int mat = blockIdx.y >> 2;
    const int n0 = (blockIdx.y & 3) * 64;
    const int mblk = blockIdx.x * 64;
    const int m0 = mblk + wave * 16;
    const bf16* wT = (mat == 0) ? wqT : (mat == 1) ? wkT : wvT;
    const float* bias = (mat == 0) ? bq : (mat == 1) ? bk : bv;

    f32x4 acc[4] = {};
    #pragma unroll
    for (int ks = 0; ks < 8; ++ks) {
        bf16x8 a = *(const bf16x8*)(xb + (size_t)(m0 + c) * 256 + ks * 32 + 8 * g);
        #pragma unroll
        for (int nf = 0; nf < 4; ++nf) {
            bf16x8 b = *(const bf16x8*)(wT + (size_t)(n0 + nf * 16 + c) * 256 + ks * 32 + 8 * g);
            acc[nf] = MFMA_16x16x32(a, b, acc[nf]);
        }
    }
    if (mat < 2) {
        bf16* out = (mat == 0) ? q : k;
        #pragma unroll
        for (int nf = 0; nf < 4; ++nf) {
            int n = n0 + nf * 16 + c;
            float bs = bias[n];
            #pragma unroll
            for (int r = 0; r < 4; ++r)
                out[(size_t)(m0 + 4 * g + r) * 256 + n] = (bf16)(acc[nf][r] + bs);
        }
    } else {
        #pragma unroll
        for (int nf = 0; nf < 4; ++nf) {
            int n = n0 + nf * 16 + c;
            float bs = bias[n];
            #pragma unroll
            for (int r = 0; r < 4; ++r)
                vt[nf * 16 + c][wave * 16 + 4 * g + r] = (bf16)(acc[nf][r] + bs);
        }
        __syncthreads();
        int bt = mblk >> 12;        // /SEQ
        int s0 = mblk & (SEQ - 1);
        int nl = threadIdx.x >> 2;  // 0..63 -> col (n offset)
        int sc = (threadIdx.x & 3) * 16;  // row (s offset) chunk
        bf16* dst = vT + ((size_t)bt * 256 + n0 + nl) * SEQ + s0 + sc;
        const bf16x8* sp = (const bf16x8*)&vt[nl][sc];
        ((bf16x8*)dst)[0] = sp[0];
        ((bf16x8*)dst)[1] = sp[1];
    }
}

// ---------------- fused attention (flash, 4-wave KV-split blocks, LDS combine) ----------------
// grid: 1024 blocks x 256 threads. Block = one 16-row q-group; wave w sweeps KV
// quarter [w*1024, w*1024+1024). Partials (o, m, l) flash-combined in LDS at the
// end (single __syncthreads in the whole kernel). Inner body = round-6 proven
// version; per-tile __syncthreads replaced by a wave-local lgkmcnt fence
// (+ sched_barrier, rule 18) so waves never lockstep.

#define ATTN_FENCE() do { \
    asm volatile("s_waitcnt lgkmcnt(0)" ::: "memory"); \
    __builtin_amdgcn_sched_barrier(0); \
} while (0)

#define LOAD_K(KF, KV)  do {                                                              \
    _Pragma("unroll")                                                                     \
    for (int ks_ = 0; ks_ < 8; ++ks_) {                                                   \
        _Pragma("unroll")                                                                 \
        for (int nf_ = 0; nf_ < 2; ++nf_)                                                 \
            KF[ks_ * 2 + nf_] = *(const bf16x8*)(kbase + (size_t)((KV) + nf_ * 16 + c) * 256 + ks_ * 32 + 8 * g); \
    } } while (0)

#define LOAD_V(VF, KV)  do {                                                              \
    _Pragma("unroll")                                                                     \
    for (int nf_ = 0; nf_ < 16; ++nf_)                                                    \
        VF[nf_] = *(const bf16x8*)(vbase + (size_t)(nf_ * 16 + c) * SEQ + (KV) + 8 * g);  \
    } while (0)

#define ATTN_BODY(KF, VF)  do {                                                           \
    f32x4 s0 = {}, s1 = {};                                                               \
    __builtin_amdgcn_s_setprio(1);                                                        \
    _Pragma("unroll")                                                                     \
    for (int ks_ = 0; ks_ < 8; ++ks_) {                                                   \
        s0 = MFMA_16x16x32(qf[ks_], KF[ks_ * 2 + 0], s0);                                 \
        s1 = MFMA_16x16x32(qf[ks_], KF[ks_ * 2 + 1], s1);                                 \
    }                                                                                     \
    __builtin_amdgcn_s_setprio(0);                                                        \
    float al[4];                                                                          \
    _Pragma("unroll")                                                                     \
    for (int r_ = 0; r_ < 4; ++r_) {                                                      \
        float v0 = s0[r_] * 0.0625f, v1 = s1[r_] * 0.0625f;                               \
        float mx = fmaxf(v0, v1);                                                         \
        mx = fmaxf(mx, __shfl_xor(mx, 1));                                                \
        mx = fmaxf(mx, __shfl_xor(mx, 2));                                                \
        mx = fmaxf(mx, __shfl_xor(mx, 4));                                                \
        mx = fmaxf(mx, __shfl_xor(mx, 8));                                                \
        float mn = fmaxf(m_run[r_], mx);                                                  \
        float a_ = __expf(m_run[r_] - mn);                                                \
        float p0 = __expf(v0 - mn), p1 = __expf(v1 - mn);                                 \
        p_lds[wave][4 * g + r_][c]      = (bf16)p0;                                       \
        p_lds[wave][4 * g + r_][16 + c] = (bf16)p1;                                       \
        float ls = p0 + p1;                                                               \
        ls += __shfl_xor(ls, 1); ls += __shfl_xor(ls, 2);                                 \
        ls += __shfl_xor(ls, 4); ls += __shfl_xor(ls, 8);                                 \
        m_run[r_] = mn; l_run[r_] = l_run[r_] * a_ + ls; al[r_] = a_;                     \
    }                                                                                     \
    _Pragma("unroll")                                                                     \
    for (int nf_ = 0; nf_ < 16; ++nf_)                                                    \
        { _Pragma("unroll") for (int r_ = 0; r_ < 4; ++r_) o[nf_][r_] *= al[r_]; }        \
    ATTN_FENCE();  /* order P ds_writes before pa ds_read (wave-local) */                 \
    bf16x8 pa = *(const bf16x8*)&p_lds[wave][c][8 * g];                                   \
    __builtin_amdgcn_s_setprio(1);                                                        \
    _Pragma("unroll")                                                                     \
    for (int nf_ = 0; nf_ < 16; ++nf_)                                                    \
        o[nf_] = MFMA_16x16x32(pa, VF[nf_], o[nf_]);                                      \
    __builtin_amdgcn_s_setprio(0);                                                        \
    ATTN_FENCE();  /* order pa ds_read before next tile's P ds_writes */                  \
} while (0)

__global__ __launch_bounds__(256, 2) void attn_kernel(
    const bf16* __restrict__ qb, const bf16* __restrict__ kb, const bf16* __restrict__ vT,
    bf16* __restrict__ attn_bf)
{
    __shared__ bf16  p_lds[4][16][40];
    __shared__ float o_lds[4][16][258];   // +2 pad: conflict-free partial writes
    __shared__ float ml_lds[4][16][2];
    const int lane = threadIdx.x & 63, wave = threadIdx.x >> 6;
    const int g = lane >> 4, c = lane & 15;
    // XCD swizzle: batch bt -> XCDs {2bt, 2bt+1}; K+V of one batch (4MB) fits one L2.
    // blockIdx.x = 2*bt + (idx&1) + 8*(idx>>1), bijective over 4 batches x 256 q-groups.
    const int low = blockIdx.x & 7, hi = blockIdx.x >> 3;
    const int bt = low >> 1;
    const int q0 = ((low & 1) + 2 * hi) * 16;
    const int mrow = bt * SEQ + q0;

    bf16x8 qf[8];
    #pragma unroll
    for (int ks = 0; ks < 8; ++ks)
        qf[ks] = *(const bf16x8*)(qb + (size_t)(mrow + c) * 256 + ks * 32 + 8 * g);

    f32x4 o[16] = {};
    float m_run[4], l_run[4];
    #pragma unroll
    for (int r = 0; r < 4; ++r) { m_run[r] = -1e30f; l_run[r] = 0.f; }

    const bf16* kbase = kb + (size_t)bt * SEQ * 256;
    const bf16* vbase = vT + (size_t)bt * 256 * SEQ;

    const int kvS = wave << 10;           // this wave's KV quarter: [kvS, kvS+1024)
    bf16x8 kfA[16], kfB[16], vf[16];
    LOAD_K(kfA, kvS);
    #pragma unroll 1
    for (int kv0 = kvS; kv0 < kvS + 1024; kv0 += 64) {
        LOAD_V(vf, kv0);
        LOAD_K(kfB, kv0 + 32);
        ATTN_BODY(kfA, vf);
        LOAD_V(vf, kv0 + 32);
        if (kv0 + 64 < kvS + 1024) LOAD_K(kfA, kv0 + 64);
        ATTN_BODY(kfB, vf);
    }

    // write partials (raw o, m, l) for flash combine
    #pragma unroll
    for (int nf = 0; nf < 16; ++nf)
        #pragma unroll
        for (int r = 0; r < 4; ++r)
            o_lds[wave][4 * g + r][nf * 16 + c] = o[nf][r];
    if (c == 0) {
        #pragma unroll
        for (int r = 0; r < 4; ++r) {
            ml_lds[wave][4 * g + r][0] = m_run[r];
            ml_lds[wave][4 * g + r][1] = l_run[r];
        }
    }
    __syncthreads();

    // combine: thread t -> row t>>4, col slice t&15
    const int row = threadIdx.x >> 4, cc = threadIdx.x & 15;
    float m0_ = ml_lds[0][row][0], m1_ = ml_lds[1][row][0];
    float m2_ = ml_lds[2][row][0], m3_ = ml_lds[3][row][0];
    float M = fmaxf(fmaxf(m0_, m1_), fmaxf(m2_, m3_));
    float e0 = __expf(m0_ - M), e1 = __expf(m1_ - M);
    float e2 = __expf(m2_ - M), e3 = __expf(m3_ - M);
    float L = ml_lds[0][row][1] * e0 + ml_lds[1][row][1] * e1
            + ml_lds[2][row][1] * e2 + ml_lds[3][row][1] * e3;
    float Linv = 1.f / L;
    #pragma unroll
    for (int j = 0; j < 16; ++j) {
        int col = j * 16 + cc;
        float O = o_lds[0][row][col] * e0 + o_lds[1][row][col] * e1
                + o_lds[2][row][col] * e2 + o_lds[3][row][col] * e3;
        attn_bf[(size_t)(mrow + row) * 256 + col] = (bf16)(O * Linv);
    }
}

// ---------------- FFN1: h = relu(attn @ w1 + b1)  (M-half pass) ----------------
__global__ __launch_bounds__(256) void ffn1_kernel(
    const bf16* __restrict__ attn, const bf16* __restrict__ w1T, const float* __restrict__ b1,
    bf16* __restrict__ h, int m_base)
{
    const int lane = threadIdx.x & 63, wave = threadIdx.x >> 6;
    const int g = lane >> 4, c = lane & 15;
    const int m0 = m_base + blockIdx.x * 64 + wave * 16;
    const int n0 = blockIdx.y * 64;

    f32x4 acc[4] = {};
    #pragma unroll
    for (int ks = 0; ks < 8; ++ks) {
        bf16x8 a = *(const bf16x8*)(attn + (size_t)(m0 + c) * 256 + ks * 32 + 8 * g);
        #pragma unroll
        for (int nf = 0; nf < 4; ++nf) {
            bf16x8 b = *(const bf16x8*)(w1T + (size_t)(n0 + nf * 16 + c) * 256 + ks * 32 + 8 * g);
            acc[nf] = MFMA_16x16x32(a, b, acc[nf]);
        }
    }
    #pragma unroll
    for (int nf = 0; nf < 4; ++nf) {
        int n = n0 + nf * 16 + c;
        float bs = b1[n];
        #pragma unroll
        for (int r = 0; r < 4; ++r) {
            float v = fmaxf(acc[nf][r] + bs, 0.f);
            h[(size_t)(m0 - m_base + 4 * g + r) * FFD + n] = (bf16)v;
        }
    }
}

// ---------------- FFN2 + residual + LayerNorm  (EXACT round-3 version, proven PASS) ----------------
// d_out is FP32 (reference output dtype is float32).
__global__ __launch_bounds__(256) void ffn2_ln_kernel(
    const bf16* __restrict__ h, const bf16* __restrict__ w2T, const float* __restrict__ b2,
    const bf16* __restrict__ attn_bf, const float* __restrict__ ln_g, const float* __restrict__ ln_b,
    float* __restrict__ out, int m_base)
{
    const int lane = threadIdx.x & 63, wave = threadIdx.x >> 6;
    const int g = lane >> 4, c = lane & 15;
    const int m0 = m_base + blockIdx.x * 64 + wave * 16;
    const int mloc = m0 - m_base;

    f32x4 acc[16] = {};
    for (int ks = 0; ks < 32; ++ks) {
        bf16x8 a = *(const bf16x8*)(h + (size_t)(mloc + c) * FFD + ks * 32 + 8 * g);
        #pragma unroll
        for (int nf = 0; nf < 16; ++nf) {
            bf16x8 b = *(const bf16x8*)(w2T + (size_t)(nf * 16 + c) * FFD + ks * 32 + 8 * g);
            acc[nf] = MFMA_16x16x32(a, b, acc[nf]);
        }
    }
    // residual + bias
    #pragma unroll
    for (int nf = 0; nf < 16; ++nf) {
        int col = nf * 16 + c;
        float bs = b2[col];
        #pragma unroll
        for (int r = 0; r < 4; ++r)
            acc[nf][r] += bs + (float)attn_bf[(size_t)(m0 + 4 * g + r) * 256 + col];
    }
    // LayerNorm stats per row (row = m0 + 4g + r; elements over 16 lanes x 16 frags)
    float sum[4] = {}, sq[4] = {};
    #pragma unroll
    for (int nf = 0; nf < 16; ++nf)
        #pragma unroll
        for (int r = 0; r < 4; ++r) { sum[r] += acc[nf][r]; sq[r] += acc[nf][r] * acc[nf][r]; }
    float mean[4], rstd[4];
    #pragma unroll
    for (int r = 0; r < 4; ++r) {
        float s_ = sum[r], q_ = sq[r];
        s_ += __shfl_xor(s_, 1); s_ += __shfl_xor(s_, 2); s_ += __shfl_xor(s_, 4); s_ += __shfl_xor(s_, 8);
        q_ += __shfl_xor(q_, 1); q_ += __shfl_xor(q_, 2); q_ += __shfl_xor(q_, 4); q_ += __shfl_xor(q_, 8);
        mean[r] = s_ * (1.f / 256.f);
        float var = q_ * (1.f / 256.f) - mean[r] * mean[r];
        rstd[r] = rsqrtf(var + 1e-5f);
    }
    #pragma unroll
    for (int nf = 0; nf < 16; ++nf) {
        int col = nf * 16 + c;
        float gg = ln_g[col], bb = ln_b[col];
        #pragma unroll
        for (int r = 0; r < 4; ++r)
            out[(size_t)(m0 + 4 * g + r) * 256 + col] = (acc[nf][r] - mean[r]) * rstd[r] * gg + bb;
    }
}

// ---------------- launch ----------------
// ws layout (bytes), total ~34 MB (proven to fit):
//   0        wqT (128K)   131072 wkT   262144 wvT
//   393216   w1T (512K)   917504 w2T (512K)      [end 1441792]
//   2097152  xb  (8M)  -> reused as attn_bf after qkv
//   10485760 qb  (8M) \
//   18874368 kb  (8M) /  -> reused as h (16M, half-M at a time) after attn
//   27262976 vT  (8M)    [end 35651584]
extern "C" void kernel_launch(void* const* d_in, const int* in_sizes, int n_in,
                              void* d_out, int out_size, void* d_ws, size_t ws_size,
                              hipStream_t stream) {
    const float* x    = (const float*)d_in[0];
    const float* wq   = (const float*)d_in[1];
    const float* bq   = (const float*)d_in[2];
    const float* wk   = (const float*)d_in[3];
    const float* bk   = (const float*)d_in[4];
    const float* wv   = (const float*)d_in[5];
    const float* bv   = (const float*)d_in[6];
    const float* w1   = (const float*)d_in[7];
    const float* b1   = (const float*)d_in[8];
    const float* w2   = (const float*)d_in[9];
    const float* b2   = (const float*)d_in[10];
    const float* ln_g = (const float*)d_in[11];
    const float* ln_b = (const float*)d_in[12];
    float* out = (float*)d_out;   // fp32 output

    char* ws = (char*)d_ws;
    bf16* wqT = (bf16*)(ws + 0);
    bf16* wkT = (bf16*)(ws + 131072);
    bf16* wvT = (bf16*)(ws + 262144);
    bf16* w1T = (bf16*)(ws + 393216);
    bf16* w2T = (bf16*)(ws + 917504);
    bf16* xb  = (bf16*)(ws + 2097152);
    bf16* qb  = (bf16*)(ws + 10485760);
    bf16* kb  = (bf16*)(ws + 18874368);
    bf16* vT  = (bf16*)(ws + 27262976);
    bf16* attn_bf = xb;   // xb dead after qkv
    bf16* hbuf    = qb;   // qb+kb dead after attn; 16 MB = half-M of h

    cast_x_kernel<<<(MTOT * HID / 4 + 255) / 256, 256, 0, stream>>>(x, xb, MTOT * HID / 4);
    transpose_cast_kernel<<<(HID * HID + 255) / 256, 256, 0, stream>>>(wq, wqT, HID, HID);
    transpose_cast_kernel<<<(HID * HID + 255) / 256, 256, 0, stream>>>(wk, wkT, HID, HID);
    transpose_cast_kernel<<<(HID * HID + 255) / 256, 256, 0, stream>>>(wv, wvT, HID, HID);
    transpose_cast_kernel<<<(HID * FFD + 255) / 256, 256, 0, stream>>>(w1, w1T, HID, FFD);
    transpose_cast_kernel<<<(FFD * HID + 255) / 256, 256, 0, stream>>>(w2, w2T, FFD, HID);

    qkv_kernel<<<dim3(MTOT / 64, 12), 256, 0, stream>>>(xb, wqT, wkT, wvT, bq, bk, bv, qb, kb, vT);
    attn_kernel<<<MTOT / 16, 256, 0, stream>>>(qb, kb, vT, attn_bf);

    const int HALF = MTOT / 2;
    for (int p = 0; p < 2; ++p) {
        ffn1_kernel<<<dim3(HALF / 64, FFD / 64), 256, 0, stream>>>(attn_bf, w1T, b1, hbuf, p * HALF);
        ffn2_ln_kernel<<<HALF / 64, 256, 0, stream>>>(hbuf, w2T, b2, attn_bf, ln_g, ln_b, out, p * HALF);
    }
}

// Round 9
// 613.439 us; speedup vs baseline: 2.0249x; 2.0249x over previous
//
#include <hip/hip_runtime.h>
#include <hip/hip_bf16.h>

typedef __bf16 bf16;
typedef __attribute__((ext_vector_type(8))) __bf16 bf16x8;
typedef __attribute__((ext_vector_type(4))) __bf16 bf16x4;
typedef __attribute__((ext_vector_type(4))) float f32x4;

#define MFMA_16x16x32(a, b, c) __builtin_amdgcn_mfma_f32_16x16x32_bf16(a, b, c, 0, 0, 0)

// Problem dims (fixed by the reference)
#define BATCH 4
#define SEQ   4096
#define HID   256
#define FFD   1024
#define MTOT  (BATCH * SEQ)   // 16384

// ---------------- prep kernels ----------------
__global__ void cast_x_kernel(const float* __restrict__ src, bf16* __restrict__ dst, int n4) {
    int i = blockIdx.x * blockDim.x + threadIdx.x;
    if (i < n4) {
        float4 v = ((const float4*)src)[i];
        bf16x4 o;
        o[0] = (bf16)v.x; o[1] = (bf16)v.y; o[2] = (bf16)v.z; o[3] = (bf16)v.w;
        ((bf16x4*)dst)[i] = o;
    }
}

// src: fp32 [R][C]  ->  dst: bf16 [C][R]   (dst[c][r] = src[r][c])
__global__ void transpose_cast_kernel(const float* __restrict__ src, bf16* __restrict__ dst,
                                      int R, int C) {
    int idx = blockIdx.x * blockDim.x + threadIdx.x;
    if (idx < R * C) {
        int r = idx / C, c = idx % C;
        dst[c * R + r] = (bf16)src[idx];
    }
}

// ---------------- QKV projection ----------------
// grid (MTOT/64, 12); blockIdx.y: 0-3 -> q cols, 4-7 -> k cols, 8-11 -> v cols
__global__ __launch_bounds__(256) void qkv_kernel(
    const bf16* __restrict__ xb,                       // [MTOT][256]
    const bf16* __restrict__ wqT, const bf16* __restrict__ wkT, const bf16* __restrict__ wvT,
    const float* __restrict__ bq, const float* __restrict__ bk, const float* __restrict__ bv,
    bf16* __restrict__ q, bf16* __restrict__ k, bf16* __restrict__ vT) // q,k: [MTOT][256]; vT: [B][256][SEQ]
{
    __shared__ bf16 vt[64][72];
    const int lane = threadIdx.x & 63, wave = threadIdx.x >> 6;
    const int g = lane >> 4, c = lane & 15;
    const int mat = blockIdx.y >> 2;
    const int n0 = (blockIdx.y & 3) * 64;
    const int mblk = blockIdx.x * 64;
    const int m0 = mblk + wave * 16;
    const bf16* wT = (mat == 0) ? wqT : (mat == 1) ? wkT : wvT;
    const float* bias = (mat == 0) ? bq : (mat == 1) ? bk : bv;

    f32x4 acc[4] = {};
    #pragma unroll
    for (int ks = 0; ks < 8; ++ks) {
        bf16x8 a = *(const bf16x8*)(xb + (size_t)(m0 + c) * 256 + ks * 32 + 8 * g);
        #pragma unroll
        for (int nf = 0; nf < 4; ++nf) {
            bf16x8 b = *(const bf16x8*)(wT + (size_t)(n0 + nf * 16 + c) * 256 + ks * 32 + 8 * g);
            acc[nf] = MFMA_16x16x32(a, b, acc[nf]);
        }
    }
    if (mat < 2) {
        bf16* out = (mat == 0) ? q : k;
        #pragma unroll
        for (int nf = 0; nf < 4; ++nf) {
            int n = n0 + nf * 16 + c;
            float bs = bias[n];
            #pragma unroll
            for (int r = 0; r < 4; ++r)
                out[(size_t)(m0 + 4 * g + r) * 256 + n] = (bf16)(acc[nf][r] + bs);
        }
    } else {
        #pragma unroll
        for (int nf = 0; nf < 4; ++nf) {
            int n = n0 + nf * 16 + c;
            float bs = bias[n];
            #pragma unroll
            for (int r = 0; r < 4; ++r)
                vt[nf * 16 + c][wave * 16 + 4 * g + r] = (bf16)(acc[nf][r] + bs);
        }
        __syncthreads();
        int bt = mblk >> 12;        // /SEQ
        int s0 = mblk & (SEQ - 1);
        int nl = threadIdx.x >> 2;  // 0..63 -> col (n offset)
        int sc = (threadIdx.x & 3) * 16;  // row (s offset) chunk
        bf16* dst = vT + ((size_t)bt * 256 + n0 + nl) * SEQ + s0 + sc;
        const bf16x8* sp = (const bf16x8*)&vt[nl][sc];
        ((bf16x8*)dst)[0] = sp[0];
        ((bf16x8*)dst)[1] = sp[1];
    }
}

// ---------------- fused attention (flash, LDS-staged KV shared by 4 waves) ----------------
// grid: 256 blocks x 256 threads. Block = 64 q-rows (wave w owns rows +16w); all
// 4 waves sweep the SAME KV stream. KVBLK=32, double-buffered LDS in FRAGMENT
// order: kstage[buf][frag][lane][8] so every ds_read_b128 is lane-contiguous
// (uniform banks, no swizzle needed). T14 split: global loads for tile t+1
// issued BEFORE compute(t) (latency hidden under MFMA), ds_writes after, one
// __syncthreads per tile. Inner math = round-6/8 proven body.

#define ATTN_FENCE() do { \
    asm volatile("s_waitcnt lgkmcnt(0)" ::: "memory"); \
    __builtin_amdgcn_sched_barrier(0); \
} while (0)

// chunk ch = i*256+tid; K: row=ch>>5, 16B-col=ch&31; V: d=ch>>2, s-chunk=ch&3.
// Global reads are lane-contiguous (full rows); LDS dst is fragment-order.
#define STAGE_GLOAD(KV) do {                                                              \
    _Pragma("unroll")                                                                     \
    for (int i_ = 0; i_ < 4; ++i_) {                                                      \
        int ch_ = i_ * 256 + tid;                                                         \
        kreg[i_] = *(const bf16x8*)(kbase + (size_t)((KV) + (ch_ >> 5)) * 256 + (ch_ & 31) * 8); \
        vreg[i_] = *(const bf16x8*)(vbase + (size_t)(ch_ >> 2) * SEQ + (KV) + (ch_ & 3) * 8);    \
    } } while (0)

#define STAGE_DSWRITE(BUF) do {                                                           \
    _Pragma("unroll")                                                                     \
    for (int i_ = 0; i_ < 4; ++i_) {                                                      \
        int ch_ = i_ * 256 + tid;                                                         \
        int kr_ = ch_ >> 5, kcb_ = ch_ & 31;                                              \
        *(bf16x8*)&kstage[BUF][(kcb_ >> 2) * 2 + (kr_ >> 4)][(kcb_ & 3) * 16 + (kr_ & 15)][0] = kreg[i_]; \
        int vd_ = ch_ >> 2, vs_ = ch_ & 3;                                                \
        *(bf16x8*)&vstage[BUF][vd_ >> 4][vs_ * 16 + (vd_ & 15)][0] = vreg[i_];            \
    } } while (0)

#define ATTN_BODY(BUF)  do {                                                              \
    f32x4 s0 = {}, s1 = {};                                                               \
    __builtin_amdgcn_s_setprio(1);                                                        \
    _Pragma("unroll")                                                                     \
    for (int ks_ = 0; ks_ < 8; ++ks_) {                                                   \
        bf16x8 k0_ = *(const bf16x8*)&kstage[BUF][ks_ * 2 + 0][lane][0];                  \
        bf16x8 k1_ = *(const bf16x8*)&kstage[BUF][ks_ * 2 + 1][lane][0];                  \
        s0 = MFMA_16x16x32(qf[ks_], k0_, s0);                                             \
        s1 = MFMA_16x16x32(qf[ks_], k1_, s1);                                             \
    }                                                                                     \
    __builtin_amdgcn_s_setprio(0);                                                        \
    float al[4];                                                                          \
    _Pragma("unroll")                                                                     \
    for (int r_ = 0; r_ < 4; ++r_) {                                                      \
        float v0 = s0[r_] * 0.0625f, v1 = s1[r_] * 0.0625f;                               \
        float mx = fmaxf(v0, v1);                                                         \
        mx = fmaxf(mx, __shfl_xor(mx, 1));                                                \
        mx = fmaxf(mx, __shfl_xor(mx, 2));                                                \
        mx = fmaxf(mx, __shfl_xor(mx, 4));                                                \
        mx = fmaxf(mx, __shfl_xor(mx, 8));                                                \
        float mn = fmaxf(m_run[r_], mx);                                                  \
        float a_ = __expf(m_run[r_] - mn);                                                \
        float p0 = __expf(v0 - mn), p1 = __expf(v1 - mn);                                 \
        p_lds[wave][4 * g + r_][c]      = (bf16)p0;                                       \
        p_lds[wave][4 * g + r_][16 + c] = (bf16)p1;                                       \
        float ls = p0 + p1;                                                               \
        ls += __shfl_xor(ls, 1); ls += __shfl_xor(ls, 2);                                 \
        ls += __shfl_xor(ls, 4); ls += __shfl_xor(ls, 8);                                 \
        m_run[r_] = mn; l_run[r_] = l_run[r_] * a_ + ls; al[r_] = a_;                     \
    }                                                                                     \
    _Pragma("unroll")                                                                     \
    for (int nf_ = 0; nf_ < 16; ++nf_)                                                    \
        { _Pragma("unroll") for (int r_ = 0; r_ < 4; ++r_) o[nf_][r_] *= al[r_]; }        \
    ATTN_FENCE();  /* order P ds_writes before pa ds_read (wave-local) */                 \
    bf16x8 pa = *(const bf16x8*)&p_lds[wave][c][8 * g];                                   \
    __builtin_amdgcn_s_setprio(1);                                                        \
    _Pragma("unroll")                                                                     \
    for (int nf_ = 0; nf_ < 16; ++nf_) {                                                  \
        bf16x8 v_ = *(const bf16x8*)&vstage[BUF][nf_][lane][0];                           \
        o[nf_] = MFMA_16x16x32(pa, v_, o[nf_]);                                           \
    }                                                                                     \
    __builtin_amdgcn_s_setprio(0);                                                        \
    ATTN_FENCE();  /* order pa ds_read before next tile's P ds_writes */                  \
} while (0)

__global__ __launch_bounds__(256, 1) void attn_kernel(
    const bf16* __restrict__ qb, const bf16* __restrict__ kb, const bf16* __restrict__ vT,
    bf16* __restrict__ attn_bf)
{
    __shared__ bf16 kstage[2][16][64][8];   // 32 KB: [buf][frag][lane][8]
    __shared__ bf16 vstage[2][16][64][8];   // 32 KB
    __shared__ bf16 p_lds[4][16][40];       // 5 KB
    const int tid = threadIdx.x;
    const int lane = tid & 63, wave = tid >> 6;
    const int g = lane >> 4, c = lane & 15;
    // XCD swizzle (256 % 8 == 0, bijective): batch bt -> XCD pair {2bt, 2bt+1};
    // one batch's K+V (4MB) per L2.
    const int low = blockIdx.x & 7, hi = blockIdx.x >> 3;
    const int bt = low >> 1;
    const int q0 = ((low & 1) + 2 * hi) * 64;
    const int mrow = bt * SEQ + q0 + wave * 16;

    bf16x8 qf[8];
    #pragma unroll
    for (int ks = 0; ks < 8; ++ks)
        qf[ks] = *(const bf16x8*)(qb + (size_t)(mrow + c) * 256 + ks * 32 + 8 * g);

    f32x4 o[16] = {};
    float m_run[4], l_run[4];
    #pragma unroll
    for (int r = 0; r < 4; ++r) { m_run[r] = -1e30f; l_run[r] = 0.f; }

    const bf16* kbase = kb + (size_t)bt * SEQ * 256;
    const bf16* vbase = vT + (size_t)bt * 256 * SEQ;

    bf16x8 kreg[4], vreg[4];
    // prologue: stage tile 0 into buf 0
    STAGE_GLOAD(0);
    STAGE_DSWRITE(0);
    __syncthreads();

    int curb = 0;
    #pragma unroll 1
    for (int t = 0; t < SEQ / 32; ++t) {
        if (t < SEQ / 32 - 1) STAGE_GLOAD((t + 1) * 32);   // issue early (T14)
        ATTN_BODY(curb);                                    // compute hides load latency
        if (t < SEQ / 32 - 1) STAGE_DSWRITE(curb ^ 1);      // write late
        __syncthreads();                                    // next tile ready; cur reads done
        curb ^= 1;
    }

    #pragma unroll
    for (int r = 0; r < 4; ++r) l_run[r] = 1.f / l_run[r];
    #pragma unroll
    for (int nf = 0; nf < 16; ++nf) {
        #pragma unroll
        for (int r = 0; r < 4; ++r) {
            float v = o[nf][r] * l_run[r];
            attn_bf[(size_t)(mrow + 4 * g + r) * 256 + nf * 16 + c] = (bf16)v;
        }
    }
}

// ---------------- FFN1: h = relu(attn @ w1 + b1)  (M-half pass) ----------------
__global__ __launch_bounds__(256) void ffn1_kernel(
    const bf16* __restrict__ attn, const bf16* __restrict__ w1T, const float* __restrict__ b1,
    bf16* __restrict__ h, int m_base)
{
    const int lane = threadIdx.x & 63, wave = threadIdx.x >> 6;
    const int g = lane >> 4, c = lane & 15;
    const int m0 = m_base + blockIdx.x * 64 + wave * 16;
    const int n0 = blockIdx.y * 64;

    f32x4 acc[4] = {};
    #pragma unroll
    for (int ks = 0; ks < 8; ++ks) {
        bf16x8 a = *(const bf16x8*)(attn + (size_t)(m0 + c) * 256 + ks * 32 + 8 * g);
        #pragma unroll
        for (int nf = 0; nf < 4; ++nf) {
            bf16x8 b = *(const bf16x8*)(w1T + (size_t)(n0 + nf * 16 + c) * 256 + ks * 32 + 8 * g);
            acc[nf] = MFMA_16x16x32(a, b, acc[nf]);
        }
    }
    #pragma unroll
    for (int nf = 0; nf < 4; ++nf) {
        int n = n0 + nf * 16 + c;
        float bs = b1[n];
        #pragma unroll
        for (int r = 0; r < 4; ++r) {
            float v = fmaxf(acc[nf][r] + bs, 0.f);
            h[(size_t)(m0 - m_base + 4 * g + r) * FFD + n] = (bf16)v;
        }
    }
}

// ---------------- FFN2 + residual + LayerNorm  (EXACT round-3 version, proven PASS) ----------------
// d_out is FP32 (reference output dtype is float32).
__global__ __launch_bounds__(256) void ffn2_ln_kernel(
    const bf16* __restrict__ h, const bf16* __restrict__ w2T, const float* __restrict__ b2,
    const bf16* __restrict__ attn_bf, const float* __restrict__ ln_g, const float* __restrict__ ln_b,
    float* __restrict__ out, int m_base)
{
    const int lane = threadIdx.x & 63, wave = threadIdx.x >> 6;
    const int g = lane >> 4, c = lane & 15;
    const int m0 = m_base + blockIdx.x * 64 + wave * 16;
    const int mloc = m0 - m_base;

    f32x4 acc[16] = {};
    for (int ks = 0; ks < 32; ++ks) {
        bf16x8 a = *(const bf16x8*)(h + (size_t)(mloc + c) * FFD + ks * 32 + 8 * g);
        #pragma unroll
        for (int nf = 0; nf < 16; ++nf) {
            bf16x8 b = *(const bf16x8*)(w2T + (size_t)(nf * 16 + c) * FFD + ks * 32 + 8 * g);
            acc[nf] = MFMA_16x16x32(a, b, acc[nf]);
        }
    }
    // residual + bias
    #pragma unroll
    for (int nf = 0; nf < 16; ++nf) {
        int col = nf * 16 + c;
        float bs = b2[col];
        #pragma unroll
        for (int r = 0; r < 4; ++r)
            acc[nf][r] += bs + (float)attn_bf[(size_t)(m0 + 4 * g + r) * 256 + col];
    }
    // LayerNorm stats per row (row = m0 + 4g + r; elements over 16 lanes x 16 frags)
    float sum[4] = {}, sq[4] = {};
    #pragma unroll
    for (int nf = 0; nf < 16; ++nf)
        #pragma unroll
        for (int r = 0; r < 4; ++r) { sum[r] += acc[nf][r]; sq[r] += acc[nf][r] * acc[nf][r]; }
    float mean[4], rstd[4];
    #pragma unroll
    for (int r = 0; r < 4; ++r) {
        float s_ = sum[r], q_ = sq[r];
        s_ += __shfl_xor(s_, 1); s_ += __shfl_xor(s_, 2); s_ += __shfl_xor(s_, 4); s_ += __shfl_xor(s_, 8);
        q_ += __shfl_xor(q_, 1); q_ += __shfl_xor(q_, 2); q_ += __shfl_xor(q_, 4); q_ += __shfl_xor(q_, 8);
        mean[r] = s_ * (1.f / 256.f);
        float var = q_ * (1.f / 256.f) - mean[r] * mean[r];
        rstd[r] = rsqrtf(var + 1e-5f);
    }
    #pragma unroll
    for (int nf = 0; nf < 16; ++nf) {
        int col = nf * 16 + c;
        float gg = ln_g[col], bb = ln_b[col];
        #pragma unroll
        for (int r = 0; r < 4; ++r)
            out[(size_t)(m0 + 4 * g + r) * 256 + col] = (acc[nf][r] - mean[r]) * rstd[r] * gg + bb;
    }
}

// ---------------- launch ----------------
// ws layout (bytes), total ~34 MB (proven to fit):
//   0        wqT (128K)   131072 wkT   262144 wvT
//   393216   w1T (512K)   917504 w2T (512K)      [end 1441792]
//   2097152  xb  (8M)  -> reused as attn_bf after qkv
//   10485760 qb  (8M) \
//   18874368 kb  (8M) /  -> reused as h (16M, half-M at a time) after attn
//   27262976 vT  (8M)    [end 35651584]
extern "C" void kernel_launch(void* const* d_in, const int* in_sizes, int n_in,
                              void* d_out, int out_size, void* d_ws, size_t ws_size,
                              hipStream_t stream) {
    const float* x    = (const float*)d_in[0];
    const float* wq   = (const float*)d_in[1];
    const float* bq   = (const float*)d_in[2];
    const float* wk   = (const float*)d_in[3];
    const float* bk   = (const float*)d_in[4];
    const float* wv   = (const float*)d_in[5];
    const float* bv   = (const float*)d_in[6];
    const float* w1   = (const float*)d_in[7];
    const float* b1   = (const float*)d_in[8];
    const float* w2   = (const float*)d_in[9];
    const float* b2   = (const float*)d_in[10];
    const float* ln_g = (const float*)d_in[11];
    const float* ln_b = (const float*)d_in[12];
    float* out = (float*)d_out;   // fp32 output

    char* ws = (char*)d_ws;
    bf16* wqT = (bf16*)(ws + 0);
    bf16* wkT = (bf16*)(ws + 131072);
    bf16* wvT = (bf16*)(ws + 262144);
    bf16* w1T = (bf16*)(ws + 393216);
    bf16* w2T = (bf16*)(ws + 917504);
    bf16* xb  = (bf16*)(ws + 2097152);
    bf16* qb  = (bf16*)(ws + 10485760);
    bf16* kb  = (bf16*)(ws + 18874368);
    bf16* vT  = (bf16*)(ws + 27262976);
    bf16* attn_bf = xb;   // xb dead after qkv
    bf16* hbuf    = qb;   // qb+kb dead after attn; 16 MB = half-M of h

    cast_x_kernel<<<(MTOT * HID / 4 + 255) / 256, 256, 0, stream>>>(x, xb, MTOT * HID / 4);
    transpose_cast_kernel<<<(HID * HID + 255) / 256, 256, 0, stream>>>(wq, wqT, HID, HID);
    transpose_cast_kernel<<<(HID * HID + 255) / 256, 256, 0, stream>>>(wk, wkT, HID, HID);
    transpose_cast_kernel<<<(HID * HID + 255) / 256, 256, 0, stream>>>(wv, wvT, HID, HID);
    transpose_cast_kernel<<<(HID * FFD + 255) / 256, 256, 0, stream>>>(w1, w1T, HID, FFD);
    transpose_cast_kernel<<<(FFD * HID + 255) / 256, 256, 0, stream>>>(w2, w2T, FFD, HID);

    qkv_kernel<<<dim3(MTOT / 64, 12), 256, 0, stream>>>(xb, wqT, wkT, wvT, bq, bk, bv, qb, kb, vT);
    attn_kernel<<<MTOT / 64, 256, 0, stream>>>(qb, kb, vT, attn_bf);

    const int HALF = MTOT / 2;
    for (int p = 0; p < 2; ++p) {
        ffn1_kernel<<<dim3(HALF / 64, FFD / 64), 256, 0, stream>>>(attn_bf, w1T, b1, hbuf, p * HALF);
        ffn2_ln_kernel<<<HALF / 64, 256, 0, stream>>>(hbuf, w2T, b2, attn_bf, ln_g, ln_b, out, p * HALF);
    }
}

// Round 10
// 506.536 us; speedup vs baseline: 2.4523x; 1.2110x over previous
//
#include <hip/hip_runtime.h>
#include <hip/hip_bf16.h>

typedef __bf16 bf16;
typedef __attribute__((ext_vector_type(8))) __bf16 bf16x8;
typedef __attribute__((ext_vector_type(4))) __bf16 bf16x4;
typedef __attribute__((ext_vector_type(4))) float f32x4;

#define MFMA_16x16x32(a, b, c) __builtin_amdgcn_mfma_f32_16x16x32_bf16(a, b, c, 0, 0, 0)

// Problem dims (fixed by the reference)
#define BATCH 4
#define SEQ   4096
#define HID   256
#define FFD   1024
#define MTOT  (BATCH * SEQ)   // 16384

// ---------------- prep kernels ----------------
__global__ void cast_x_kernel(const float* __restrict__ src, bf16* __restrict__ dst, int n4) {
    int i = blockIdx.x * blockDim.x + threadIdx.x;
    if (i < n4) {
        float4 v = ((const float4*)src)[i];
        bf16x4 o;
        o[0] = (bf16)v.x; o[1] = (bf16)v.y; o[2] = (bf16)v.z; o[3] = (bf16)v.w;
        ((bf16x4*)dst)[i] = o;
    }
}

// src: fp32 [R][C]  ->  dst: bf16 [C][R]   (dst[c][r] = src[r][c])
__global__ void transpose_cast_kernel(const float* __restrict__ src, bf16* __restrict__ dst,
                                      int R, int C) {
    int idx = blockIdx.x * blockDim.x + threadIdx.x;
    if (idx < R * C) {
        int r = idx / C, c = idx % C;
        dst[c * R + r] = (bf16)src[idx];
    }
}

// ---------------- QKV projection ----------------
// grid (MTOT/64, 12); blockIdx.y: 0-3 -> q cols, 4-7 -> k cols, 8-11 -> v cols
__global__ __launch_bounds__(256) void qkv_kernel(
    const bf16* __restrict__ xb,                       // [MTOT][256]
    const bf16* __restrict__ wqT, const bf16* __restrict__ wkT, const bf16* __restrict__ wvT,
    const float* __restrict__ bq, const float* __restrict__ bk, const float* __restrict__ bv,
    bf16* __restrict__ q, bf16* __restrict__ k, bf16* __restrict__ vT) // q,k: [MTOT][256]; vT: [B][256][SEQ]
{
    __shared__ bf16 vt[64][72];
    const int lane = threadIdx.x & 63, wave = threadIdx.x >> 6;
    const int g = lane >> 4, c = lane & 15;
    const int mat = blockIdx.y >> 2;
    const int n0 = (blockIdx.y & 3) * 64;
    const int mblk = blockIdx.x * 64;
    const int m0 = mblk + wave * 16;
    const bf16* wT = (mat == 0) ? wqT : (mat == 1) ? wkT : wvT;
    const float* bias = (mat == 0) ? bq : (mat == 1) ? bk : bv;

    f32x4 acc[4] = {};
    #pragma unroll
    for (int ks = 0; ks < 8; ++ks) {
        bf16x8 a = *(const bf16x8*)(xb + (size_t)(m0 + c) * 256 + ks * 32 + 8 * g);
        #pragma unroll
        for (int nf = 0; nf < 4; ++nf) {
            bf16x8 b = *(const bf16x8*)(wT + (size_t)(n0 + nf * 16 + c) * 256 + ks * 32 + 8 * g);
            acc[nf] = MFMA_16x16x32(a, b, acc[nf]);
        }
    }
    if (mat < 2) {
        bf16* out = (mat == 0) ? q : k;
        #pragma unroll
        for (int nf = 0; nf < 4; ++nf) {
            int n = n0 + nf * 16 + c;
            float bs = bias[n];
            #pragma unroll
            for (int r = 0; r < 4; ++r)
                out[(size_t)(m0 + 4 * g + r) * 256 + n] = (bf16)(acc[nf][r] + bs);
        }
    } else {
        #pragma unroll
        for (int nf = 0; nf < 4; ++nf) {
            int n = n0 + nf * 16 + c;
            float bs = bias[n];
            #pragma unroll
            for (int r = 0; r < 4; ++r)
                vt[nf * 16 + c][wave * 16 + 4 * g + r] = (bf16)(acc[nf][r] + bs);
        }
        __syncthreads();
        int bt = mblk >> 12;        // /SEQ
        int s0 = mblk & (SEQ - 1);
        int nl = threadIdx.x >> 2;  // 0..63 -> col (n offset)
        int sc = (threadIdx.x & 3) * 16;  // row (s offset) chunk
        bf16* dst = vT + ((size_t)bt * 256 + n0 + nl) * SEQ + s0 + sc;
        const bf16x8* sp = (const bf16x8*)&vt[nl][sc];
        ((bf16x8*)dst)[0] = sp[0];
        ((bf16x8*)dst)[1] = sp[1];
    }
}

// ---------------- fused attention (flash, LDS-staged KV shared by 4 waves) ----------------
// grid: 256 blocks x 256 threads. Block = 64 q-rows (wave w owns rows +16w); all
// 4 waves sweep the SAME KV stream. KVBLK=32, double-buffered LDS in fragment
// order. K-stage uses XOR swizzle l' = l ^ ((l>>3)&6) on BOTH write and read:
// without it the transpose write hits banks 0..7 only (round-9: 4.25e7
// conflicts ~ 20% of kernel time); with it writes spread 8 lanes/bank-group
// (optimal) and reads stay a bijection (conflict-free). V-stage write pattern
// is naturally optimal (analyzed) - no swizzle.
// T13 defer-max: skip rescale when no row's max grew (bit-identical math).

#define ATTN_FENCE() do { \
    asm volatile("s_waitcnt lgkmcnt(0)" ::: "memory"); \
    __builtin_amdgcn_sched_barrier(0); \
} while (0)

// chunk ch = i*256+tid; K: row=ch>>5, 16B-col=ch&31; V: d=ch>>2, s-chunk=ch&3.
// Global reads are lane-contiguous (full rows); LDS dst is fragment-order.
#define STAGE_GLOAD(KV) do {                                                              \
    _Pragma("unroll")                                                                     \
    for (int i_ = 0; i_ < 4; ++i_) {                                                      \
        int ch_ = i_ * 256 + tid;                                                         \
        kreg[i_] = *(const bf16x8*)(kbase + (size_t)((KV) + (ch_ >> 5)) * 256 + (ch_ & 31) * 8); \
        vreg[i_] = *(const bf16x8*)(vbase + (size_t)(ch_ >> 2) * SEQ + (KV) + (ch_ & 3) * 8);    \
    } } while (0)

#define STAGE_DSWRITE(BUF) do {                                                           \
    _Pragma("unroll")                                                                     \
    for (int i_ = 0; i_ < 4; ++i_) {                                                      \
        int ch_ = i_ * 256 + tid;                                                         \
        int kr_ = ch_ >> 5, kcb_ = ch_ & 31;                                              \
        int kf_ = (kcb_ >> 2) * 2 + (kr_ >> 4);                                           \
        int kl_ = (kcb_ & 3) * 16 + (kr_ & 15);                                           \
        *(bf16x8*)&kstage[BUF][kf_][kl_ ^ ((kl_ >> 3) & 6)][0] = kreg[i_];                \
        int vd_ = ch_ >> 2, vs_ = ch_ & 3;                                                \
        *(bf16x8*)&vstage[BUF][vd_ >> 4][vs_ * 16 + (vd_ & 15)][0] = vreg[i_];            \
    } } while (0)

#define ATTN_BODY(BUF)  do {                                                              \
    f32x4 s0 = {}, s1 = {};                                                               \
    __builtin_amdgcn_s_setprio(1);                                                        \
    _Pragma("unroll")                                                                     \
    for (int ks_ = 0; ks_ < 8; ++ks_) {                                                   \
        bf16x8 k0_ = *(const bf16x8*)&kstage[BUF][ks_ * 2 + 0][kln][0];                   \
        bf16x8 k1_ = *(const bf16x8*)&kstage[BUF][ks_ * 2 + 1][kln][0];                   \
        s0 = MFMA_16x16x32(qf[ks_], k0_, s0);                                             \
        s1 = MFMA_16x16x32(qf[ks_], k1_, s1);                                             \
    }                                                                                     \
    __builtin_amdgcn_s_setprio(0);                                                        \
    float vv0[4], vv1[4], mx[4];                                                          \
    _Pragma("unroll")                                                                     \
    for (int r_ = 0; r_ < 4; ++r_) {                                                      \
        vv0[r_] = s0[r_] * 0.0625f; vv1[r_] = s1[r_] * 0.0625f;                           \
        float m_ = fmaxf(vv0[r_], vv1[r_]);                                               \
        m_ = fmaxf(m_, __shfl_xor(m_, 1));                                                \
        m_ = fmaxf(m_, __shfl_xor(m_, 2));                                                \
        m_ = fmaxf(m_, __shfl_xor(m_, 4));                                                \
        m_ = fmaxf(m_, __shfl_xor(m_, 8));                                                \
        mx[r_] = m_;                                                                      \
    }                                                                                     \
    float need = fmaxf(fmaxf(mx[0] - m_run[0], mx[1] - m_run[1]),                         \
                       fmaxf(mx[2] - m_run[2], mx[3] - m_run[3]));                        \
    if (__any(need > 0.f)) {   /* T13: rescale only when some row max grew */             \
        float al[4];                                                                      \
        _Pragma("unroll")                                                                 \
        for (int r_ = 0; r_ < 4; ++r_) {                                                  \
            float mn = fmaxf(m_run[r_], mx[r_]);                                          \
            al[r_] = __expf(m_run[r_] - mn);                                              \
            m_run[r_] = mn; l_run[r_] *= al[r_];                                          \
        }                                                                                 \
        _Pragma("unroll")                                                                 \
        for (int nf_ = 0; nf_ < 16; ++nf_)                                                \
            { _Pragma("unroll") for (int r_ = 0; r_ < 4; ++r_) o[nf_][r_] *= al[r_]; }    \
    }                                                                                     \
    _Pragma("unroll")                                                                     \
    for (int r_ = 0; r_ < 4; ++r_) {                                                      \
        float p0 = __expf(vv0[r_] - m_run[r_]), p1 = __expf(vv1[r_] - m_run[r_]);         \
        p_lds[wave][4 * g + r_][c]      = (bf16)p0;                                       \
        p_lds[wave][4 * g + r_][16 + c] = (bf16)p1;                                       \
        float ls = p0 + p1;                                                               \
        ls += __shfl_xor(ls, 1); ls += __shfl_xor(ls, 2);                                 \
        ls += __shfl_xor(ls, 4); ls += __shfl_xor(ls, 8);                                 \
        l_run[r_] += ls;                                                                  \
    }                                                                                     \
    ATTN_FENCE();  /* order P ds_writes before pa ds_read (wave-local) */                 \
    bf16x8 pa = *(const bf16x8*)&p_lds[wave][c][8 * g];                                   \
    __builtin_amdgcn_s_setprio(1);                                                        \
    _Pragma("unroll")                                                                     \
    for (int nf_ = 0; nf_ < 16; ++nf_) {                                                  \
        bf16x8 v_ = *(const bf16x8*)&vstage[BUF][nf_][lane][0];                           \
        o[nf_] = MFMA_16x16x32(pa, v_, o[nf_]);                                           \
    }                                                                                     \
    __builtin_amdgcn_s_setprio(0);                                                        \
    ATTN_FENCE();  /* order pa ds_read before next tile's P ds_writes */                  \
} while (0)

__global__ __launch_bounds__(256, 1) void attn_kernel(
    const bf16* __restrict__ qb, const bf16* __restrict__ kb, const bf16* __restrict__ vT,
    bf16* __restrict__ attn_bf)
{
    __shared__ bf16 kstage[2][16][64][8];   // 32 KB: [buf][frag][lane'][8], lane' = l^((l>>3)&6)
    __shared__ bf16 vstage[2][16][64][8];   // 32 KB
    __shared__ bf16 p_lds[4][16][40];       // 5 KB
    const int tid = threadIdx.x;
    const int lane = tid & 63, wave = tid >> 6;
    const int g = lane >> 4, c = lane & 15;
    const int kln = lane ^ ((lane >> 3) & 6);   // swizzled K read slot
    // XCD swizzle (256 % 8 == 0, bijective): batch bt -> XCD pair {2bt, 2bt+1};
    // one batch's K+V (4MB) per L2.
    const int low = blockIdx.x & 7, hi = blockIdx.x >> 3;
    const int bt = low >> 1;
    const int q0 = ((low & 1) + 2 * hi) * 64;
    const int mrow = bt * SEQ + q0 + wave * 16;

    bf16x8 qf[8];
    #pragma unroll
    for (int ks = 0; ks < 8; ++ks)
        qf[ks] = *(const bf16x8*)(qb + (size_t)(mrow + c) * 256 + ks * 32 + 8 * g);

    f32x4 o[16] = {};
    float m_run[4], l_run[4];
    #pragma unroll
    for (int r = 0; r < 4; ++r) { m_run[r] = -1e30f; l_run[r] = 0.f; }

    const bf16* kbase = kb + (size_t)bt * SEQ * 256;
    const bf16* vbase = vT + (size_t)bt * 256 * SEQ;

    bf16x8 kreg[4], vreg[4];
    // prologue: stage tile 0 into buf 0
    STAGE_GLOAD(0);
    STAGE_DSWRITE(0);
    __syncthreads();

    int curb = 0;
    #pragma unroll 1
    for (int t = 0; t < SEQ / 32; ++t) {
        if (t < SEQ / 32 - 1) STAGE_GLOAD((t + 1) * 32);   // issue early (T14)
        ATTN_BODY(curb);                                    // compute hides load latency
        if (t < SEQ / 32 - 1) STAGE_DSWRITE(curb ^ 1);      // write late
        __syncthreads();                                    // next tile ready; cur reads done
        curb ^= 1;
    }

    #pragma unroll
    for (int r = 0; r < 4; ++r) l_run[r] = 1.f / l_run[r];
    #pragma unroll
    for (int nf = 0; nf < 16; ++nf) {
        #pragma unroll
        for (int r = 0; r < 4; ++r) {
            float v = o[nf][r] * l_run[r];
            attn_bf[(size_t)(mrow + 4 * g + r) * 256 + nf * 16 + c] = (bf16)v;
        }
    }
}

// ---------------- FFN1: h = relu(attn @ w1 + b1)  (M-half pass) ----------------
__global__ __launch_bounds__(256) void ffn1_kernel(
    const bf16* __restrict__ attn, const bf16* __restrict__ w1T, const float* __restrict__ b1,
    bf16* __restrict__ h, int m_base)
{
    const int lane = threadIdx.x & 63, wave = threadIdx.x >> 6;
    const int g = lane >> 4, c = lane & 15;
    const int m0 = m_base + blockIdx.x * 64 + wave * 16;
    const int n0 = blockIdx.y * 64;

    f32x4 acc[4] = {};
    #pragma unroll
    for (int ks = 0; ks < 8; ++ks) {
        bf16x8 a = *(const bf16x8*)(attn + (size_t)(m0 + c) * 256 + ks * 32 + 8 * g);
        #pragma unroll
        for (int nf = 0; nf < 4; ++nf) {
            bf16x8 b = *(const bf16x8*)(w1T + (size_t)(n0 + nf * 16 + c) * 256 + ks * 32 + 8 * g);
            acc[nf] = MFMA_16x16x32(a, b, acc[nf]);
        }
    }
    #pragma unroll
    for (int nf = 0; nf < 4; ++nf) {
        int n = n0 + nf * 16 + c;
        float bs = b1[n];
        #pragma unroll
        for (int r = 0; r < 4; ++r) {
            float v = fmaxf(acc[nf][r] + bs, 0.f);
            h[(size_t)(m0 - m_base + 4 * g + r) * FFD + n] = (bf16)v;
        }
    }
}

// ---------------- FFN2 + residual + LayerNorm  (round-3 math, regridded to 1-wave blocks) ----
// d_out is FP32 (reference output dtype is float32). 512 blocks/pass x 64 thr
// (was 128 x 256: 0.5 block/CU left half the GPU idle).
__global__ __launch_bounds__(64) void ffn2_ln_kernel(
    const bf16* __restrict__ h, const bf16* __restrict__ w2T, const float* __restrict__ b2,
    const bf16* __restrict__ attn_bf, const float* __restrict__ ln_g, const float* __restrict__ ln_b,
    float* __restrict__ out, int m_base)
{
    const int lane = threadIdx.x & 63;
    const int g = lane >> 4, c = lane & 15;
    const int m0 = m_base + blockIdx.x * 16;
    const int mloc = m0 - m_base;

    f32x4 acc[16] = {};
    for (int ks = 0; ks < 32; ++ks) {
        bf16x8 a = *(const bf16x8*)(h + (size_t)(mloc + c) * FFD + ks * 32 + 8 * g);
        #pragma unroll
        for (int nf = 0; nf < 16; ++nf) {
            bf16x8 b = *(const bf16x8*)(w2T + (size_t)(nf * 16 + c) * FFD + ks * 32 + 8 * g);
            acc[nf] = MFMA_16x16x32(a, b, acc[nf]);
        }
    }
    // residual + bias
    #pragma unroll
    for (int nf = 0; nf < 16; ++nf) {
        int col = nf * 16 + c;
        float bs = b2[col];
        #pragma unroll
        for (int r = 0; r < 4; ++r)
            acc[nf][r] += bs + (float)attn_bf[(size_t)(m0 + 4 * g + r) * 256 + col];
    }
    // LayerNorm stats per row (row = m0 + 4g + r; elements over 16 lanes x 16 frags)
    float sum[4] = {}, sq[4] = {};
    #pragma unroll
    for (int nf = 0; nf < 16; ++nf)
        #pragma unroll
        for (int r = 0; r < 4; ++r) { sum[r] += acc[nf][r]; sq[r] += acc[nf][r] * acc[nf][r]; }
    float mean[4], rstd[4];
    #pragma unroll
    for (int r = 0; r < 4; ++r) {
        float s_ = sum[r], q_ = sq[r];
        s_ += __shfl_xor(s_, 1); s_ += __shfl_xor(s_, 2); s_ += __shfl_xor(s_, 4); s_ += __shfl_xor(s_, 8);
        q_ += __shfl_xor(q_, 1); q_ += __shfl_xor(q_, 2); q_ += __shfl_xor(q_, 4); q_ += __shfl_xor(q_, 8);
        mean[r] = s_ * (1.f / 256.f);
        float var = q_ * (1.f / 256.f) - mean[r] * mean[r];
        rstd[r] = rsqrtf(var + 1e-5f);
    }
    #pragma unroll
    for (int nf = 0; nf < 16; ++nf) {
        int col = nf * 16 + c;
        float gg = ln_g[col], bb = ln_b[col];
        #pragma unroll
        for (int r = 0; r < 4; ++r)
            out[(size_t)(m0 + 4 * g + r) * 256 + col] = (acc[nf][r] - mean[r]) * rstd[r] * gg + bb;
    }
}

// ---------------- launch ----------------
// ws layout (bytes), total ~34 MB (proven to fit):
//   0        wqT (128K)   131072 wkT   262144 wvT
//   393216   w1T (512K)   917504 w2T (512K)      [end 1441792]
//   2097152  xb  (8M)  -> reused as attn_bf after qkv
//   10485760 qb  (8M) \
//   18874368 kb  (8M) /  -> reused as h (16M, half-M at a time) after attn
//   27262976 vT  (8M)    [end 35651584]
extern "C" void kernel_launch(void* const* d_in, const int* in_sizes, int n_in,
                              void* d_out, int out_size, void* d_ws, size_t ws_size,
                              hipStream_t stream) {
    const float* x    = (const float*)d_in[0];
    const float* wq   = (const float*)d_in[1];
    const float* bq   = (const float*)d_in[2];
    const float* wk   = (const float*)d_in[3];
    const float* bk   = (const float*)d_in[4];
    const float* wv   = (const float*)d_in[5];
    const float* bv   = (const float*)d_in[6];
    const float* w1   = (const float*)d_in[7];
    const float* b1   = (const float*)d_in[8];
    const float* w2   = (const float*)d_in[9];
    const float* b2   = (const float*)d_in[10];
    const float* ln_g = (const float*)d_in[11];
    const float* ln_b = (const float*)d_in[12];
    float* out = (float*)d_out;   // fp32 output

    char* ws = (char*)d_ws;
    bf16* wqT = (bf16*)(ws + 0);
    bf16* wkT = (bf16*)(ws + 131072);
    bf16* wvT = (bf16*)(ws + 262144);
    bf16* w1T = (bf16*)(ws + 393216);
    bf16* w2T = (bf16*)(ws + 917504);
    bf16* xb  = (bf16*)(ws + 2097152);
    bf16* qb  = (bf16*)(ws + 10485760);
    bf16* kb  = (bf16*)(ws + 18874368);
    bf16* vT  = (bf16*)(ws + 27262976);
    bf16* attn_bf = xb;   // xb dead after qkv
    bf16* hbuf    = qb;   // qb+kb dead after attn; 16 MB = half-M of h

    cast_x_kernel<<<(MTOT * HID / 4 + 255) / 256, 256, 0, stream>>>(x, xb, MTOT * HID / 4);
    transpose_cast_kernel<<<(HID * HID + 255) / 256, 256, 0, stream>>>(wq, wqT, HID, HID);
    transpose_cast_kernel<<<(HID * HID + 255) / 256, 256, 0, stream>>>(wk, wkT, HID, HID);
    transpose_cast_kernel<<<(HID * HID + 255) / 256, 256, 0, stream>>>(wv, wvT, HID, HID);
    transpose_cast_kernel<<<(HID * FFD + 255) / 256, 256, 0, stream>>>(w1, w1T, HID, FFD);
    transpose_cast_kernel<<<(FFD * HID + 255) / 256, 256, 0, stream>>>(w2, w2T, FFD, HID);

    qkv_kernel<<<dim3(MTOT / 64, 12), 256, 0, stream>>>(xb, wqT, wkT, wvT, bq, bk, bv, qb, kb, vT);
    attn_kernel<<<MTOT / 64, 256, 0, stream>>>(qb, kb, vT, attn_bf);

    const int HALF = MTOT / 2;
    for (int p = 0; p < 2; ++p) {
        ffn1_kernel<<<dim3(HALF / 64, FFD / 64), 256, 0, stream>>>(attn_bf, w1T, b1, hbuf, p * HALF);
        ffn2_ln_kernel<<<HALF / 16, 64, 0, stream>>>(hbuf, w2T, b2, attn_bf, ln_g, ln_b, out, p * HALF);
    }
}

// Round 11
// 443.711 us; speedup vs baseline: 2.7995x; 1.1416x over previous
//
#include <hip/hip_runtime.h>
#include <hip/hip_bf16.h>

typedef __bf16 bf16;
typedef __attribute__((ext_vector_type(8))) __bf16 bf16x8;
typedef __attribute__((ext_vector_type(4))) __bf16 bf16x4;
typedef __attribute__((ext_vector_type(4))) float f32x4;

#define MFMA_16x16x32(a, b, c) __builtin_amdgcn_mfma_f32_16x16x32_bf16(a, b, c, 0, 0, 0)

// Problem dims (fixed by the reference)
#define BATCH 4
#define SEQ   4096
#define HID   256
#define FFD   1024
#define MTOT  (BATCH * SEQ)   // 16384

// ---------------- prep kernels ----------------
__global__ void cast_x_kernel(const float* __restrict__ src, bf16* __restrict__ dst, int n4) {
    int i = blockIdx.x * blockDim.x + threadIdx.x;
    if (i < n4) {
        float4 v = ((const float4*)src)[i];
        bf16x4 o;
        o[0] = (bf16)v.x; o[1] = (bf16)v.y; o[2] = (bf16)v.z; o[3] = (bf16)v.w;
        ((bf16x4*)dst)[i] = o;
    }
}

// src: fp32 [R][C]  ->  dst: bf16 [C][R]   (dst[c][r] = src[r][c])
__global__ void transpose_cast_kernel(const float* __restrict__ src, bf16* __restrict__ dst,
                                      int R, int C) {
    int idx = blockIdx.x * blockDim.x + threadIdx.x;
    if (idx < R * C) {
        int r = idx / C, c = idx % C;
        dst[c * R + r] = (bf16)src[idx];
    }
}

// ---------------- QKV projection ----------------
// grid (MTOT/64, 12); blockIdx.y: 0-3 -> q cols, 4-7 -> k cols, 8-11 -> v cols
__global__ __launch_bounds__(256) void qkv_kernel(
    const bf16* __restrict__ xb,                       // [MTOT][256]
    const bf16* __restrict__ wqT, const bf16* __restrict__ wkT, const bf16* __restrict__ wvT,
    const float* __restrict__ bq, const float* __restrict__ bk, const float* __restrict__ bv,
    bf16* __restrict__ q, bf16* __restrict__ k, bf16* __restrict__ vT) // q,k: [MTOT][256]; vT: [B][256][SEQ]
{
    __shared__ bf16 vt[64][72];
    const int lane = threadIdx.x & 63, wave = threadIdx.x >> 6;
    const int g = lane >> 4, c = lane & 15;
    const int mat = blockIdx.y >> 2;
    const int n0 = (blockIdx.y & 3) * 64;
    const int mblk = blockIdx.x * 64;
    const int m0 = mblk + wave * 16;
    const bf16* wT = (mat == 0) ? wqT : (mat == 1) ? wkT : wvT;
    const float* bias = (mat == 0) ? bq : (mat == 1) ? bk : bv;

    f32x4 acc[4] = {};
    #pragma unroll
    for (int ks = 0; ks < 8; ++ks) {
        bf16x8 a = *(const bf16x8*)(xb + (size_t)(m0 + c) * 256 + ks * 32 + 8 * g);
        #pragma unroll
        for (int nf = 0; nf < 4; ++nf) {
            bf16x8 b = *(const bf16x8*)(wT + (size_t)(n0 + nf * 16 + c) * 256 + ks * 32 + 8 * g);
            acc[nf] = MFMA_16x16x32(a, b, acc[nf]);
        }
    }
    if (mat < 2) {
        bf16* out = (mat == 0) ? q : k;
        #pragma unroll
        for (int nf = 0; nf < 4; ++nf) {
            int n = n0 + nf * 16 + c;
            float bs = bias[n];
            #pragma unroll
            for (int r = 0; r < 4; ++r)
                out[(size_t)(m0 + 4 * g + r) * 256 + n] = (bf16)(acc[nf][r] + bs);
        }
    } else {
        #pragma unroll
        for (int nf = 0; nf < 4; ++nf) {
            int n = n0 + nf * 16 + c;
            float bs = bias[n];
            #pragma unroll
            for (int r = 0; r < 4; ++r)
                vt[nf * 16 + c][wave * 16 + 4 * g + r] = (bf16)(acc[nf][r] + bs);
        }
        __syncthreads();
        int bt = mblk >> 12;        // /SEQ
        int s0 = mblk & (SEQ - 1);
        int nl = threadIdx.x >> 2;  // 0..63 -> col (n offset)
        int sc = (threadIdx.x & 3) * 16;  // row (s offset) chunk
        bf16* dst = vT + ((size_t)bt * 256 + n0 + nl) * SEQ + s0 + sc;
        const bf16x8* sp = (const bf16x8*)&vt[nl][sc];
        ((bf16x8*)dst)[0] = sp[0];
        ((bf16x8*)dst)[1] = sp[1];
    }
}

// ---------------- fused attention (flash, LDS-staged KV, swapped QK^T, in-reg softmax) ----
// grid: 256 blocks x 256 threads. Block = 64 q-rows (wave w owns rows +16w); all
// 4 waves sweep the SAME KV stream. KVBLK=32, double-buffered LDS.
// Swapped QK^T: s = mfma(K_frag, Q_frag) -> lane(g,c) holds S^T for q=c at
// kv = {4g+r, 16+4g+r}. Row softmax = 7 in-lane fmax + 2 shfls (xor16/32);
// P stays in registers as the PV A-fragment under kv(g,j) = (j<4)?4g+j:16+4g+(j-4)
// (round-7-proven mapping). V is STAGED in that order so PV B-frags are single
// 16B LDS reads. K staging layout/swizzle identical to round-10 (A-frag == old
// B-frag layout); only the MFMA operand order flips. p_lds + fences deleted.
// T13 defer-max: skip rescale when no lane's row max grew (bit-identical).

// chunk ch = i*256+tid; K: row=ch>>5, 16B-col=ch&31; V: d=ch>>2, s-chunk=ch&3.
#define STAGE_GLOAD(KV) do {                                                              \
    _Pragma("unroll")                                                                     \
    for (int i_ = 0; i_ < 4; ++i_) {                                                      \
        int ch_ = i_ * 256 + tid;                                                         \
        kreg[i_] = *(const bf16x8*)(kbase + (size_t)((KV) + (ch_ >> 5)) * 256 + (ch_ & 31) * 8); \
        vreg[i_] = *(const bf16x8*)(vbase + (size_t)(ch_ >> 2) * SEQ + (KV) + (ch_ & 3) * 8);    \
    } } while (0)

#define STAGE_DSWRITE(BUF) do {                                                           \
    _Pragma("unroll")                                                                     \
    for (int i_ = 0; i_ < 4; ++i_) {                                                      \
        int ch_ = i_ * 256 + tid;                                                         \
        int kr_ = ch_ >> 5, kcb_ = ch_ & 31;                                              \
        int kf_ = (kcb_ >> 2) * 2 + (kr_ >> 4);                                           \
        int kl_ = (kcb_ & 3) * 16 + (kr_ & 15);                                           \
        *(bf16x8*)&kstage[BUF][kf_][kl_ ^ ((kl_ >> 3) & 6)][0] = kreg[i_];                \
        int vd_ = ch_ >> 2, vs_ = ch_ & 3;                                                \
        int g1_ = 2 * (vs_ & 1), jh_ = (vs_ >> 1) * 4;                                    \
        bf16x4 lo_ = ((const bf16x4*)&vreg[i_])[0];                                       \
        bf16x4 hi_ = ((const bf16x4*)&vreg[i_])[1];                                       \
        *(bf16x4*)&vstage[BUF][vd_ >> 4][g1_ * 16 + (vd_ & 15)][jh_]        = lo_;        \
        *(bf16x4*)&vstage[BUF][vd_ >> 4][g1_ * 16 + 16 + (vd_ & 15)][jh_]   = hi_;        \
    } } while (0)

#define ATTN_BODY(BUF)  do {                                                              \
    f32x4 s0 = {}, s1 = {};                                                               \
    __builtin_amdgcn_s_setprio(1);                                                        \
    _Pragma("unroll")                                                                     \
    for (int ks_ = 0; ks_ < 8; ++ks_) {                                                   \
        bf16x8 k0_ = *(const bf16x8*)&kstage[BUF][ks_ * 2 + 0][kln][0];                   \
        bf16x8 k1_ = *(const bf16x8*)&kstage[BUF][ks_ * 2 + 1][kln][0];                   \
        s0 = MFMA_16x16x32(k0_, qf[ks_], s0);                                             \
        s1 = MFMA_16x16x32(k1_, qf[ks_], s1);                                             \
    }                                                                                     \
    __builtin_amdgcn_s_setprio(0);                                                        \
    float p_[8];                                                                          \
    _Pragma("unroll")                                                                     \
    for (int r_ = 0; r_ < 4; ++r_) { p_[r_] = s0[r_] * 0.0625f; p_[4 + r_] = s1[r_] * 0.0625f; } \
    float mx = fmaxf(fmaxf(fmaxf(p_[0], p_[1]), fmaxf(p_[2], p_[3])),                     \
                     fmaxf(fmaxf(p_[4], p_[5]), fmaxf(p_[6], p_[7])));                    \
    mx = fmaxf(mx, __shfl_xor(mx, 16));                                                   \
    mx = fmaxf(mx, __shfl_xor(mx, 32));                                                   \
    if (__any(mx > m_run)) {   /* T13: rescale only when some row max grew */             \
        float mn = fmaxf(m_run, mx);                                                      \
        float a_ = __expf(m_run - mn);                                                    \
        m_run = mn; l_run *= a_;                                                          \
        float a0_ = __shfl(a_, 4 * g + 0), a1_ = __shfl(a_, 4 * g + 1);                   \
        float a2_ = __shfl(a_, 4 * g + 2), a3_ = __shfl(a_, 4 * g + 3);                   \
        _Pragma("unroll")                                                                 \
        for (int nf_ = 0; nf_ < 16; ++nf_) {                                              \
            o[nf_][0] *= a0_; o[nf_][1] *= a1_; o[nf_][2] *= a2_; o[nf_][3] *= a3_;       \
        }                                                                                 \
    }                                                                                     \
    float ls = 0.f;                                                                       \
    _Pragma("unroll")                                                                     \
    for (int j_ = 0; j_ < 8; ++j_) { p_[j_] = __expf(p_[j_] - m_run); ls += p_[j_]; }     \
    ls += __shfl_xor(ls, 16);                                                             \
    ls += __shfl_xor(ls, 32);                                                             \
    l_run += ls;                                                                          \
    bf16x8 pa;                                                                            \
    _Pragma("unroll")                                                                     \
    for (int j_ = 0; j_ < 8; ++j_) pa[j_] = (bf16)p_[j_];                                 \
    __builtin_amdgcn_s_setprio(1);                                                        \
    _Pragma("unroll")                                                                     \
    for (int nf_ = 0; nf_ < 16; ++nf_) {                                                  \
        bf16x8 v_ = *(const bf16x8*)&vstage[BUF][nf_][lane][0];                           \
        o[nf_] = MFMA_16x16x32(pa, v_, o[nf_]);                                           \
    }                                                                                     \
    __builtin_amdgcn_s_setprio(0);                                                        \
} while (0)

__global__ __launch_bounds__(256, 1) void attn_kernel(
    const bf16* __restrict__ qb, const bf16* __restrict__ kb, const bf16* __restrict__ vT,
    bf16* __restrict__ attn_bf)
{
    __shared__ bf16 kstage[2][16][64][8];   // 32 KB: [buf][frag][slot'][8], slot' = l^((l>>3)&6)
    __shared__ bf16 vstage[2][16][64][8];   // 32 KB: [buf][d-frag][16g+c][kv(g,j)]
    const int tid = threadIdx.x;
    const int lane = tid & 63, wave = tid >> 6;
    const int g = lane >> 4, c = lane & 15;
    const int kln = lane ^ ((lane >> 3) & 6);   // swizzled K read slot
    // XCD swizzle (256 % 8 == 0, bijective): batch bt -> XCD pair {2bt, 2bt+1};
    // one batch's K+V (4MB) per L2.
    const int low = blockIdx.x & 7, hi = blockIdx.x >> 3;
    const int bt = low >> 1;
    const int q0 = ((low & 1) + 2 * hi) * 64;
    const int mrow = bt * SEQ + q0 + wave * 16;

    bf16x8 qf[8];
    #pragma unroll
    for (int ks = 0; ks < 8; ++ks)
        qf[ks] = *(const bf16x8*)(qb + (size_t)(mrow + c) * 256 + ks * 32 + 8 * g);

    f32x4 o[16] = {};
    float m_run = -1e30f, l_run = 0.f;    // per-lane: softmax state for q-row = c

    const bf16* kbase = kb + (size_t)bt * SEQ * 256;
    const bf16* vbase = vT + (size_t)bt * 256 * SEQ;

    bf16x8 kreg[4], vreg[4];
    // prologue: stage tile 0 into buf 0
    STAGE_GLOAD(0);
    STAGE_DSWRITE(0);
    __syncthreads();

    int curb = 0;
    #pragma unroll 1
    for (int t = 0; t < SEQ / 32; ++t) {
        if (t < SEQ / 32 - 1) STAGE_GLOAD((t + 1) * 32);   // issue early (T14)
        ATTN_BODY(curb);                                    // compute hides load latency
        if (t < SEQ / 32 - 1) STAGE_DSWRITE(curb ^ 1);      // write late
        __syncthreads();                                    // next tile ready; cur reads done
        curb ^= 1;
    }

    float linv = 1.f / l_run;
    float l0 = __shfl(linv, 4 * g + 0), l1 = __shfl(linv, 4 * g + 1);
    float l2 = __shfl(linv, 4 * g + 2), l3 = __shfl(linv, 4 * g + 3);
    #pragma unroll
    for (int nf = 0; nf < 16; ++nf) {
        attn_bf[(size_t)(mrow + 4 * g + 0) * 256 + nf * 16 + c] = (bf16)(o[nf][0] * l0);
        attn_bf[(size_t)(mrow + 4 * g + 1) * 256 + nf * 16 + c] = (bf16)(o[nf][1] * l1);
        attn_bf[(size_t)(mrow + 4 * g + 2) * 256 + nf * 16 + c] = (bf16)(o[nf][2] * l2);
        attn_bf[(size_t)(mrow + 4 * g + 3) * 256 + nf * 16 + c] = (bf16)(o[nf][3] * l3);
    }
}

// ---------------- FFN1: h = relu(attn @ w1 + b1)  (M-half pass) ----------------
__global__ __launch_bounds__(256) void ffn1_kernel(
    const bf16* __restrict__ attn, const bf16* __restrict__ w1T, const float* __restrict__ b1,
    bf16* __restrict__ h, int m_base)
{
    const int lane = threadIdx.x & 63, wave = threadIdx.x >> 6;
    const int g = lane >> 4, c = lane & 15;
    const int m0 = m_base + blockIdx.x * 64 + wave * 16;
    const int n0 = blockIdx.y * 64;

    f32x4 acc[4] = {};
    #pragma unroll
    for (int ks = 0; ks < 8; ++ks) {
        bf16x8 a = *(const bf16x8*)(attn + (size_t)(m0 + c) * 256 + ks * 32 + 8 * g);
        #pragma unroll
        for (int nf = 0; nf < 4; ++nf) {
            bf16x8 b = *(const bf16x8*)(w1T + (size_t)(n0 + nf * 16 + c) * 256 + ks * 32 + 8 * g);
            acc[nf] = MFMA_16x16x32(a, b, acc[nf]);
        }
    }
    #pragma unroll
    for (int nf = 0; nf < 4; ++nf) {
        int n = n0 + nf * 16 + c;
        float bs = b1[n];
        #pragma unroll
        for (int r = 0; r < 4; ++r) {
            float v = fmaxf(acc[nf][r] + bs, 0.f);
            h[(size_t)(m0 - m_base + 4 * g + r) * FFD + n] = (bf16)v;
        }
    }
}

// ---------------- FFN2 + residual + LayerNorm  (round-3 math, 1-wave blocks) ----------------
// d_out is FP32 (reference output dtype is float32). 512 blocks/pass x 64 thr.
__global__ __launch_bounds__(64) void ffn2_ln_kernel(
    const bf16* __restrict__ h, const bf16* __restrict__ w2T, const float* __restrict__ b2,
    const bf16* __restrict__ attn_bf, const float* __restrict__ ln_g, const float* __restrict__ ln_b,
    float* __restrict__ out, int m_base)
{
    const int lane = threadIdx.x & 63;
    const int g = lane >> 4, c = lane & 15;
    const int m0 = m_base + blockIdx.x * 16;
    const int mloc = m0 - m_base;

    f32x4 acc[16] = {};
    for (int ks = 0; ks < 32; ++ks) {
        bf16x8 a = *(const bf16x8*)(h + (size_t)(mloc + c) * FFD + ks * 32 + 8 * g);
        #pragma unroll
        for (int nf = 0; nf < 16; ++nf) {
            bf16x8 b = *(const bf16x8*)(w2T + (size_t)(nf * 16 + c) * FFD + ks * 32 + 8 * g);
            acc[nf] = MFMA_16x16x32(a, b, acc[nf]);
        }
    }
    // residual + bias
    #pragma unroll
    for (int nf = 0; nf < 16; ++nf) {
        int col = nf * 16 + c;
        float bs = b2[col];
        #pragma unroll
        for (int r = 0; r < 4; ++r)
            acc[nf][r] += bs + (float)attn_bf[(size_t)(m0 + 4 * g + r) * 256 + col];
    }
    // LayerNorm stats per row (row = m0 + 4g + r; elements over 16 lanes x 16 frags)
    float sum[4] = {}, sq[4] = {};
    #pragma unroll
    for (int nf = 0; nf < 16; ++nf)
        #pragma unroll
        for (int r = 0; r < 4; ++r) { sum[r] += acc[nf][r]; sq[r] += acc[nf][r] * acc[nf][r]; }
    float mean[4], rstd[4];
    #pragma unroll
    for (int r = 0; r < 4; ++r) {
        float s_ = sum[r], q_ = sq[r];
        s_ += __shfl_xor(s_, 1); s_ += __shfl_xor(s_, 2); s_ += __shfl_xor(s_, 4); s_ += __shfl_xor(s_, 8);
        q_ += __shfl_xor(q_, 1); q_ += __shfl_xor(q_, 2); q_ += __shfl_xor(q_, 4); q_ += __shfl_xor(q_, 8);
        mean[r] = s_ * (1.f / 256.f);
        float var = q_ * (1.f / 256.f) - mean[r] * mean[r];
        rstd[r] = rsqrtf(var + 1e-5f);
    }
    #pragma unroll
    for (int nf = 0; nf < 16; ++nf) {
        int col = nf * 16 + c;
        float gg = ln_g[col], bb = ln_b[col];
        #pragma unroll
        for (int r = 0; r < 4; ++r)
            out[(size_t)(m0 + 4 * g + r) * 256 + col] = (acc[nf][r] - mean[r]) * rstd[r] * gg + bb;
    }
}

// ---------------- launch ----------------
// ws layout (bytes), total ~34 MB (proven to fit; rounds 1-2 showed >=94MB also works):
//   0        wqT (128K)   131072 wkT   262144 wvT
//   393216   w1T (512K)   917504 w2T (512K)      [end 1441792]
//   2097152  xb  (8M)  -> reused as attn_bf after qkv
//   10485760 qb  (8M) \
//   18874368 kb  (8M) /  -> reused as h (16M, half-M at a time) after attn
//   27262976 vT  (8M)    [end 35651584]
extern "C" void kernel_launch(void* const* d_in, const int* in_sizes, int n_in,
                              void* d_out, int out_size, void* d_ws, size_t ws_size,
                              hipStream_t stream) {
    const float* x    = (const float*)d_in[0];
    const float* wq   = (const float*)d_in[1];
    const float* bq   = (const float*)d_in[2];
    const float* wk   = (const float*)d_in[3];
    const float* bk   = (const float*)d_in[4];
    const float* wv   = (const float*)d_in[5];
    const float* bv   = (const float*)d_in[6];
    const float* w1   = (const float*)d_in[7];
    const float* b1   = (const float*)d_in[8];
    const float* w2   = (const float*)d_in[9];
    const float* b2   = (const float*)d_in[10];
    const float* ln_g = (const float*)d_in[11];
    const float* ln_b = (const float*)d_in[12];
    float* out = (float*)d_out;   // fp32 output

    char* ws = (char*)d_ws;
    bf16* wqT = (bf16*)(ws + 0);
    bf16* wkT = (bf16*)(ws + 131072);
    bf16* wvT = (bf16*)(ws + 262144);
    bf16* w1T = (bf16*)(ws + 393216);
    bf16* w2T = (bf16*)(ws + 917504);
    bf16* xb  = (bf16*)(ws + 2097152);
    bf16* qb  = (bf16*)(ws + 10485760);
    bf16* kb  = (bf16*)(ws + 18874368);
    bf16* vT  = (bf16*)(ws + 27262976);
    bf16* attn_bf = xb;   // xb dead after qkv
    bf16* hbuf    = qb;   // qb+kb dead after attn; 16 MB = half-M of h

    cast_x_kernel<<<(MTOT * HID / 4 + 255) / 256, 256, 0, stream>>>(x, xb, MTOT * HID / 4);
    transpose_cast_kernel<<<(HID * HID + 255) / 256, 256, 0, stream>>>(wq, wqT, HID, HID);
    transpose_cast_kernel<<<(HID * HID + 255) / 256, 256, 0, stream>>>(wk, wkT, HID, HID);
    transpose_cast_kernel<<<(HID * HID + 255) / 256, 256, 0, stream>>>(wv, wvT, HID, HID);
    transpose_cast_kernel<<<(HID * FFD + 255) / 256, 256, 0, stream>>>(w1, w1T, HID, FFD);
    transpose_cast_kernel<<<(FFD * HID + 255) / 256, 256, 0, stream>>>(w2, w2T, FFD, HID);

    qkv_kernel<<<dim3(MTOT / 64, 12), 256, 0, stream>>>(xb, wqT, wkT, wvT, bq, bk, bv, qb, kb, vT);
    attn_kernel<<<MTOT / 64, 256, 0, stream>>>(qb, kb, vT, attn_bf);

    const int HALF = MTOT / 2;
    for (int p = 0; p < 2; ++p) {
        ffn1_kernel<<<dim3(HALF / 64, FFD / 64), 256, 0, stream>>>(attn_bf, w1T, b1, hbuf, p * HALF);
        ffn2_ln_kernel<<<HALF / 16, 64, 0, stream>>>(hbuf, w2T, b2, attn_bf, ln_g, ln_b, out, p * HALF);
    }
}